// Round 4
// 1456.578 us; speedup vs baseline: 1.2984x; 1.2984x over previous
//
#include <hip/hip_runtime.h>
#include <hip/hip_bf16.h>

// Problem dims
#define S_LEN 256
#define EDIM  256
#define HDIM  512
#define BDIM  512
#define LOUT  8
// v5: v2's 256-CU XCD-grouped structure + v1's PROVEN coherence path.
// v2/v3/v4 (sc0-only data path) all failed at absmax~5e-2: sc0 alone is not
// a reliable L1 bypass on gfx950 (LLVM gfx940+ legalizer: agent=SC1,
// system=SC0+SC1 -- sc0 alone can be satisfied by stale L1). Rather than a
// 4th scope guess, revert the h-exchange to the exact op pair proven in v1:
//   producer: sc0 sc1 store -> vmcnt(0) -> barrier -> AGENT atomic add
//   consumer: AGENT atomic spin load -> barrier -> sc0 sc1 data loads
// Structure kept from v2: 16 groups, each BT=32 batch rows x 16 WGs (HT=32
// h-cols). 256 WGs x ~153KB LDS => capacity-pinned 1 WG/CU => 32 WGs/XCD;
// groups formed per-XCD via HW_REG_XCC_ID (keeps flag+data traffic XCD-local
// even though the coherence point is the MALL).
#define BT    32     // batch rows per group
#define HT    32     // h cols per WG
#define NHT   16     // WGs per group (barrier width)
#define NGRP  16
// LDS strides (bf16 elems). 520*2B=1040B row stride -> 2-way bank alias (free).
#define WHH_STRIDE 520
#define WIH_STRIDE 264
#define HST_STRIDE 40    // h staging, ushort elems (80B rows)
#define HBUF (BDIM * HDIM)   // elems per h bf16 buffer
#define SPIN_CAP 2000000     // safety net only; proven path terminates normally

typedef short bf16x8 __attribute__((ext_vector_type(8)));
typedef float f32x4  __attribute__((ext_vector_type(4)));
typedef unsigned int u32x4 __attribute__((ext_vector_type(4)));

__device__ __forceinline__ unsigned short f2b(float f) {
    unsigned u = __float_as_uint(f);
    u += 0x7FFFu + ((u >> 16) & 1u);   // round-to-nearest-even
    return (unsigned short)(u >> 16);
}
__device__ __forceinline__ float sigmoid_(float x) { return 1.0f / (1.0f + __expf(-x)); }
__device__ __forceinline__ float tanh_(float x)    { return 2.0f / (1.0f + __expf(-2.0f * x)) - 1.0f; }

// v1-proven coherent (system-scope) 16B accesses. sc0 sc1 => coherent point
// (memory-side cache); pairs correctly with AGENT-scope flag atomics.
__device__ __forceinline__ void gst_b128_sys(u32x4 v, void* addr) {
    asm volatile("global_store_dwordx4 %0, %1, off sc0 sc1" :: "v"(addr), "v"(v) : "memory");
}
__device__ __forceinline__ u32x4 gld_b128_sys(const void* addr) {
    u32x4 v;
    asm volatile("global_load_dwordx4 %0, %1, off sc0 sc1" : "=&v"(v) : "v"(addr) : "memory");
    return v;
}
__device__ __forceinline__ void wait_vm0() {
    asm volatile("s_waitcnt vmcnt(0)" ::: "memory");
}

// ---------------------------------------------------------------- cast x -> bf16
__global__ __launch_bounds__(256) void cast_f32_bf16(const float* __restrict__ in,
                                                     unsigned short* __restrict__ out,
                                                     int n4) {
    int i = blockIdx.x * blockDim.x + threadIdx.x;
    int stride = gridDim.x * blockDim.x;
    for (int idx = i; idx < n4; idx += stride) {
        float4 v = ((const float4*)in)[idx];
        ushort4 o;
        o.x = f2b(v.x); o.y = f2b(v.y); o.z = f2b(v.z); o.w = f2b(v.w);
        ((ushort4*)out)[idx] = o;
    }
}

// ---------------------------------------------------------------- persistent GRU scan
__global__ __launch_bounds__(256) void gru_scan(
    const float* __restrict__ W_ih, const float* __restrict__ W_hh,
    const float* __restrict__ b_ih, const float* __restrict__ b_hh,
    const unsigned short* __restrict__ x16,   // [B, S, E] bf16
    unsigned short* __restrict__ h16,         // 2 x [B, H] bf16 (double buffer)
    float* __restrict__ h32_out,              // [B, H] final hidden
    int* __restrict__ flags)                  // [NGRP, S] arrive counters + [16] claim cnts
{
    const int tid  = threadIdx.x;
    const int wave = tid >> 6;
    const int lane = tid & 63;
    const int quad = lane >> 4;
    const int nl   = lane & 15;
    const int rt   = wave & 1;   // row-tile (16 rows) within BT=32
    const int ct   = wave >> 1;  // col-tile (16 cols) within HT=32

    __shared__ unsigned short Whh_l[96 * WHH_STRIDE];  // [gate(3) x 32 cols] x 512 k  (99.8 KB)
    __shared__ unsigned short Wih_l[96 * WIH_STRIDE];  // [gate(3) x 32 cols] x 256 k  (50.7 KB)
    __shared__ unsigned short hstage[BT * HST_STRIDE]; // pack C-layout -> row-major 16B chunks
    __shared__ int role_s;

    // ---- claim a role on this physical XCD (1 WG/CU by LDS capacity => 32 WGs/XCD)
    int* cnt = flags + NGRP * S_LEN;
    if (tid == 0) {
        unsigned xcc;
        asm volatile("s_getreg_b32 %0, hwreg(HW_REG_XCC_ID, 0, 32)" : "=s"(xcc));
        int xcd = (int)(xcc & 7u);
        int r = __hip_atomic_fetch_add(&cnt[xcd], 1, __ATOMIC_RELAXED,
                                       __HIP_MEMORY_SCOPE_AGENT);
        role_s = xcd * 32 + (r & 31);
    }
    __syncthreads();
    const int role = role_s;
    const int g  = (role >> 5) * 2 + ((role >> 4) & 1);  // group 0..15 (2 per XCD)
    const int ht = role & 15;                            // h-col slot within group
    const int jt = ht * HT;

    // ---- stage W_hh slice (96 rows x 512), fp32 -> bf16
    for (int f4 = tid; f4 < 96 * 128; f4 += 256) {
        int lr = f4 >> 7, c4 = f4 & 127;
        int grow = (lr >> 5) * HDIM + jt + (lr & 31);    // gate*512 + jt + c
        float4 v = ((const float4*)(W_hh + (size_t)grow * HDIM))[c4];
        ushort4 o; o.x = f2b(v.x); o.y = f2b(v.y); o.z = f2b(v.z); o.w = f2b(v.w);
        *(ushort4*)&Whh_l[lr * WHH_STRIDE + c4 * 4] = o;
    }
    // ---- stage W_ih slice (96 rows x 256)
    for (int f4 = tid; f4 < 96 * 64; f4 += 256) {
        int lr = f4 >> 6, c4 = f4 & 63;
        int grow = (lr >> 5) * HDIM + jt + (lr & 31);
        float4 v = ((const float4*)(W_ih + (size_t)grow * EDIM))[c4];
        ushort4 o; o.x = f2b(v.x); o.y = f2b(v.y); o.z = f2b(v.z); o.w = f2b(v.w);
        *(ushort4*)&Wih_l[lr * WIH_STRIDE + c4 * 4] = o;
    }
    __syncthreads();

    // A-operand pointers (A row = nl within this wave's 16-row tile)
    const int brow = g * BT + rt * 16 + nl;
    const unsigned short* xrow = x16 + (size_t)brow * S_LEN * EDIM + quad * 8;
    const size_t hoff = (size_t)brow * HDIM + quad * 8;

    // LDS B-fragment bases: row = gate*32 + ct*16 + nl
    int wih_b[3], whh_b[3];
    #pragma unroll
    for (int gg = 0; gg < 3; ++gg) {
        wih_b[gg] = (gg * 32 + ct * 16 + nl) * WIH_STRIDE + quad * 8;
        whh_b[gg] = (gg * 32 + ct * 16 + nl) * WHH_STRIDE + quad * 8;
    }

    // per-thread output column (C layout: col = nl) + biases
    const int jc = jt + ct * 16 + nl;
    const float bir = b_ih[jc],        bhr = b_hh[jc];
    const float biz = b_ih[512 + jc],  bhz = b_hh[512 + jc];
    const float bin = b_ih[1024 + jc], bhn = b_hh[1024 + jc];

    float hreg[4] = {0.f, 0.f, 0.f, 0.f};   // h carried in C layout (rows quad*4+r)
    const int flg_base = g * S_LEN;
    int dead = 0;                           // tid0-only spin dead-latch (safety net)

    // preload x A-fragments for step 0
    bf16x8 xf[8];
    #pragma unroll
    for (int kk = 0; kk < 8; ++kk) xf[kk] = *(const bf16x8*)(xrow + kk * 32);

    for (int s = 0; s < S_LEN; ++s) {
        f32x4 ar  = (f32x4){0.f,0.f,0.f,0.f};
        f32x4 az  = (f32x4){0.f,0.f,0.f,0.f};
        f32x4 anx = (f32x4){0.f,0.f,0.f,0.f};
        f32x4 anh = (f32x4){0.f,0.f,0.f,0.f};

        // ---- x-side GEMM for step s (overlaps producers of h[s] finishing)
        #pragma unroll
        for (int kk = 0; kk < 8; ++kk) {
            bf16x8 a = xf[kk];
            ar  = __builtin_amdgcn_mfma_f32_16x16x32_bf16(a, *(const bf16x8*)&Wih_l[wih_b[0] + kk * 32], ar,  0, 0, 0);
            az  = __builtin_amdgcn_mfma_f32_16x16x32_bf16(a, *(const bf16x8*)&Wih_l[wih_b[1] + kk * 32], az,  0, 0, 0);
            anx = __builtin_amdgcn_mfma_f32_16x16x32_bf16(a, *(const bf16x8*)&Wih_l[wih_b[2] + kk * 32], anx, 0, 0, 0);
        }

        // ---- wait for h[s] complete (all 16 producers of this group)
        if (s > 0) {
            if (tid == 0 && !dead) {
                const int* fp = flags + flg_base + (s - 1);
                int it = 0;
                while (__hip_atomic_load(fp, __ATOMIC_RELAXED,
                                         __HIP_MEMORY_SCOPE_AGENT) < NHT) {
                    __builtin_amdgcn_s_sleep(2);
                    if (++it > SPIN_CAP) { dead = 1; break; }
                }
            }
            __syncthreads();
        }

        // ---- coherent A-fragment loads of h[s] (proven sc0 sc1 path)
        const unsigned short* hp = h16 + (size_t)(s & 1) * HBUF + hoff;
        u32x4 ha[16];
        #pragma unroll
        for (int kk = 0; kk < 16; ++kk) ha[kk] = gld_b128_sys(hp + kk * 32);
        wait_vm0();
        // rule #18: inline-asm loads are invisible to compiler waitcnt insertion;
        // "memory" clobber does not order register-only MFMAs. Pin MFMAs below.
        __builtin_amdgcn_sched_barrier(0);

        // ---- prefetch next step's x A-fragments (overlaps h-GEMM)
        if (s + 1 < S_LEN) {
            const unsigned short* xp = xrow + (size_t)(s + 1) * EDIM;
            #pragma unroll
            for (int kk = 0; kk < 8; ++kk) xf[kk] = *(const bf16x8*)(xp + kk * 32);
        }

        // ---- h-side GEMM
        #pragma unroll
        for (int kk = 0; kk < 16; ++kk) {
            union { u32x4 u; bf16x8 b; } cv; cv.u = ha[kk];
            bf16x8 a = cv.b;
            ar  = __builtin_amdgcn_mfma_f32_16x16x32_bf16(a, *(const bf16x8*)&Whh_l[whh_b[0] + kk * 32], ar,  0, 0, 0);
            az  = __builtin_amdgcn_mfma_f32_16x16x32_bf16(a, *(const bf16x8*)&Whh_l[whh_b[1] + kk * 32], az,  0, 0, 0);
            anh = __builtin_amdgcn_mfma_f32_16x16x32_bf16(a, *(const bf16x8*)&Whh_l[whh_b[2] + kk * 32], anh, 0, 0, 0);
        }

        // ---- gate math in C-layout registers (row = rt*16 + quad*4 + r, col = jc)
        #pragma unroll
        for (int r = 0; r < 4; ++r) {
            float rr = sigmoid_(ar[r] + bir + bhr);
            float zz = sigmoid_(az[r] + biz + bhz);
            float nn = tanh_(anx[r] + bin + rr * (anh[r] + bhn));
            float hn = (1.0f - zz) * nn + zz * hreg[r];
            hreg[r] = hn;
            hstage[(rt * 16 + quad * 4 + r) * HST_STRIDE + ct * 16 + nl] = f2b(hn);
        }
        __syncthreads();

        // ---- pack to 16B chunks, coherent store (proven sc0 sc1 path)
        if (tid < 128) {
            int row = tid >> 2, ch = tid & 3;
            u32x4 v = *(const u32x4*)&hstage[row * HST_STRIDE + ch * 8];
            unsigned short* dst = h16 + (size_t)((s + 1) & 1) * HBUF
                                + (size_t)(g * BT + row) * HDIM + jt + ch * 8;
            gst_b128_sys(v, dst);
        }
        wait_vm0();        // drain this thread's coherent stores
        __syncthreads();   // all threads' stores globally visible
        if (tid == 0) {
            __hip_atomic_fetch_add(flags + flg_base + s, 1, __ATOMIC_RELAXED,
                                   __HIP_MEMORY_SCOPE_AGENT);
        }
    }

    // ---- final hidden state to fp32 global for the head
    #pragma unroll
    for (int r = 0; r < 4; ++r)
        h32_out[(size_t)(g * BT + rt * 16 + quad * 4 + r) * HDIM + jc] = hreg[r];
}

// ---------------------------------------------------------------- head: logits + softmax
__global__ __launch_bounds__(256) void out_head(const float* __restrict__ h32,
                                                const float* __restrict__ W_out,
                                                const float* __restrict__ b_out,
                                                float* __restrict__ out) {
    int b = blockIdx.x * blockDim.x + threadIdx.x;   // 0..511
    if (b >= BDIM) return;
    float acc[LOUT];
    #pragma unroll
    for (int l = 0; l < LOUT; ++l) acc[l] = b_out[l];
    const float4* hrow = (const float4*)(h32 + (size_t)b * HDIM);
    for (int k4 = 0; k4 < HDIM / 4; ++k4) {
        float4 hv = hrow[k4];
        #pragma unroll
        for (int l = 0; l < LOUT; ++l) {
            const float4 wv = ((const float4*)(W_out + l * HDIM))[k4];
            acc[l] += hv.x * wv.x + hv.y * wv.y + hv.z * wv.z + hv.w * wv.w;
        }
    }
    float m = acc[0];
    #pragma unroll
    for (int l = 1; l < LOUT; ++l) m = fmaxf(m, acc[l]);
    float sum = 0.f;
    #pragma unroll
    for (int l = 0; l < LOUT; ++l) { acc[l] = __expf(acc[l] - m); sum += acc[l]; }
    float inv = 1.0f / sum;
    float4 o0 = {acc[0] * inv, acc[1] * inv, acc[2] * inv, acc[3] * inv};
    float4 o1 = {acc[4] * inv, acc[5] * inv, acc[6] * inv, acc[7] * inv};
    ((float4*)(out + (size_t)b * LOUT))[0] = o0;
    ((float4*)(out + (size_t)b * LOUT))[1] = o1;
}

// ---------------------------------------------------------------- launch
extern "C" void kernel_launch(void* const* d_in, const int* in_sizes, int n_in,
                              void* d_out, int out_size, void* d_ws, size_t ws_size,
                              hipStream_t stream) {
    const float* x     = (const float*)d_in[0];
    const float* W_ih  = (const float*)d_in[1];
    const float* W_hh  = (const float*)d_in[2];
    const float* b_ih  = (const float*)d_in[3];
    const float* b_hh  = (const float*)d_in[4];
    const float* W_out = (const float*)d_in[5];
    const float* b_out = (const float*)d_in[6];
    float* out = (float*)d_out;

    char* w = (char*)d_ws;
    unsigned short* x16 = (unsigned short*)w;  w += (size_t)BDIM * S_LEN * EDIM * 2;  // 67 MB
    unsigned short* h16 = (unsigned short*)w;  w += (size_t)2 * HBUF * 2;             // 1 MB
    float* h32          = (float*)w;           w += (size_t)BDIM * HDIM * 4;          // 1 MB
    int* flags          = (int*)w;             w += (size_t)(NGRP * S_LEN + 16) * 4;  // ~16 KB

    (void)hipMemsetAsync(flags, 0, (NGRP * S_LEN + 16) * sizeof(int), stream);
    (void)hipMemsetAsync(h16, 0, HBUF * sizeof(unsigned short), stream);  // h[0] = 0

    const int n4 = (BDIM * S_LEN * EDIM) / 4;
    cast_f32_bf16<<<8192, 256, 0, stream>>>(x, x16, n4);

    // 256 WGs x ~153 KB LDS: capacity-pins exactly 1 WG/CU => 32 WGs per XCD.
    gru_scan<<<256, 256, 0, stream>>>(W_ih, W_hh, b_ih, b_hh, x16, h16, h32, flags);

    out_head<<<2, 256, 0, stream>>>(h32, W_out, b_out, out);
}

// Round 5
// 1447.550 us; speedup vs baseline: 1.3065x; 1.0062x over previous
//
#include <hip/hip_runtime.h>
#include <hip/hip_bf16.h>

// Problem dims
#define S_LEN 256
#define EDIM  256
#define HDIM  512
#define BDIM  512
#define LOUT  8
// v6: XCD-local exchange on the per-XCD L2.
// v2-v4 failed because sc0 alone = SE scope (SC[1:0]: 00=CU, 01=SE, 10=Device,
// 11=System) and our 16-CU groups span 4 SEs -> stale L1 across SE boundary.
// v5 (proven): sc0 sc1 (System) via the MALL = correct but ~4.4us/step of
// exchange latency. v6 uses sc1 (Device): bypass L1, served by the XCD's
// shared L2 -- producer+consumer share that L2 by construction (XCD-claimed
// groups), so dirty lines are hit directly; no wbl2/inv, no MALL.
// Flags: per-producer monotone counters (16B padded), plain sc1 stores +
// wave0 64-lane sc1 poll -- removes the 16-atomic MALL train of v5.
// Structure (from v5): 16 groups, each BT=32 batch rows x 16 WGs (HT=32
// h-cols). 256 WGs x ~153KB LDS => capacity-pinned 1 WG/CU => 32 WGs/XCD;
// groups formed per-XCD via HW_REG_XCC_ID.
#define BT    32     // batch rows per group
#define HT    32     // h cols per WG
#define NHT   16     // WGs per group (barrier width)
#define NGRP  16
// LDS strides (bf16 elems). 520*2B=1040B row stride -> 2-way bank alias (free).
#define WHH_STRIDE 520
#define WIH_STRIDE 264
#define HST_STRIDE 40    // h staging, ushort elems (80B rows)
#define HBUF (BDIM * HDIM)   // elems per h bf16 buffer
#define SPIN_CAP 2000000     // safety net: dead-latch (fail, not hang)

typedef short bf16x8 __attribute__((ext_vector_type(8)));
typedef float f32x4  __attribute__((ext_vector_type(4)));
typedef unsigned int u32x4 __attribute__((ext_vector_type(4)));

__device__ __forceinline__ unsigned short f2b(float f) {
    unsigned u = __float_as_uint(f);
    u += 0x7FFFu + ((u >> 16) & 1u);   // round-to-nearest-even
    return (unsigned short)(u >> 16);
}
__device__ __forceinline__ float sigmoid_(float x) { return 1.0f / (1.0f + __expf(-x)); }
__device__ __forceinline__ float tanh_(float x)    { return 2.0f / (1.0f + __expf(-2.0f * x)) - 1.0f; }

// Device-scope (sc1) ops: bypass L1, normal lookup in the local XCD L2.
// Correct here because producer and consumer share that L2 (same XCD).
__device__ __forceinline__ void gst_b128_dev(u32x4 v, void* addr) {
    asm volatile("global_store_dwordx4 %0, %1, off sc1" :: "v"(addr), "v"(v) : "memory");
}
__device__ __forceinline__ u32x4 gld_b128_dev(const void* addr) {
    u32x4 v;
    asm volatile("global_load_dwordx4 %0, %1, off sc1" : "=&v"(v) : "v"(addr) : "memory");
    return v;
}
__device__ __forceinline__ void gst_b32_dev(int v, void* addr) {
    asm volatile("global_store_dword %0, %1, off sc1" :: "v"(addr), "v"(v) : "memory");
}
__device__ __forceinline__ int gld_b32_dev(const void* addr) {
    int v;
    asm volatile("global_load_dword %0, %1, off sc1\n\ts_waitcnt vmcnt(0)"
                 : "=&v"(v) : "v"(addr) : "memory");
    return v;
}
__device__ __forceinline__ void wait_vm0() {
    asm volatile("s_waitcnt vmcnt(0)" ::: "memory");
}

// ---------------------------------------------------------------- cast x -> bf16
__global__ __launch_bounds__(256) void cast_f32_bf16(const float* __restrict__ in,
                                                     unsigned short* __restrict__ out,
                                                     int n4) {
    int i = blockIdx.x * blockDim.x + threadIdx.x;
    int stride = gridDim.x * blockDim.x;
    for (int idx = i; idx < n4; idx += stride) {
        float4 v = ((const float4*)in)[idx];
        ushort4 o;
        o.x = f2b(v.x); o.y = f2b(v.y); o.z = f2b(v.z); o.w = f2b(v.w);
        ((ushort4*)out)[idx] = o;
    }
}

// ---------------------------------------------------------------- persistent GRU scan
__global__ __launch_bounds__(256) void gru_scan(
    const float* __restrict__ W_ih, const float* __restrict__ W_hh,
    const float* __restrict__ b_ih, const float* __restrict__ b_hh,
    const unsigned short* __restrict__ x16,   // [B, S, E] bf16
    unsigned short* __restrict__ h16,         // 2 x [B, H] bf16 (double buffer)
    float* __restrict__ h32_out,              // [B, H] final hidden
    int* __restrict__ flags)                  // [NGRP*16*4] step flags + [16] claim cnts
{
    const int tid  = threadIdx.x;
    const int wave = tid >> 6;
    const int lane = tid & 63;
    const int quad = lane >> 4;
    const int nl   = lane & 15;
    const int rt   = wave & 1;   // row-tile (16 rows) within BT=32
    const int ct   = wave >> 1;  // col-tile (16 cols) within HT=32

    __shared__ unsigned short Whh_l[96 * WHH_STRIDE];  // [gate(3) x 32 cols] x 512 k  (99.8 KB)
    __shared__ unsigned short Wih_l[96 * WIH_STRIDE];  // [gate(3) x 32 cols] x 256 k  (50.7 KB)
    __shared__ unsigned short hstage[BT * HST_STRIDE]; // pack C-layout -> row-major 16B chunks
    __shared__ int role_s;

    // ---- claim a role on this physical XCD (1 WG/CU by LDS capacity => 32 WGs/XCD)
    int* cnt = flags + NGRP * 16 * 4;
    if (tid == 0) {
        unsigned xcc;
        asm volatile("s_getreg_b32 %0, hwreg(HW_REG_XCC_ID, 0, 32)" : "=s"(xcc));
        int xcd = (int)(xcc & 7u);
        int r = __hip_atomic_fetch_add(&cnt[xcd], 1, __ATOMIC_RELAXED,
                                       __HIP_MEMORY_SCOPE_AGENT);
        role_s = xcd * 32 + (r & 31);
    }
    __syncthreads();
    const int role = role_s;
    const int g  = (role >> 5) * 2 + ((role >> 4) & 1);  // group 0..15 (2 per XCD)
    const int ht = role & 15;                            // h-col slot within group
    const int jt = ht * HT;

    // ---- stage W_hh slice (96 rows x 512), fp32 -> bf16
    for (int f4 = tid; f4 < 96 * 128; f4 += 256) {
        int lr = f4 >> 7, c4 = f4 & 127;
        int grow = (lr >> 5) * HDIM + jt + (lr & 31);    // gate*512 + jt + c
        float4 v = ((const float4*)(W_hh + (size_t)grow * HDIM))[c4];
        ushort4 o; o.x = f2b(v.x); o.y = f2b(v.y); o.z = f2b(v.z); o.w = f2b(v.w);
        *(ushort4*)&Whh_l[lr * WHH_STRIDE + c4 * 4] = o;
    }
    // ---- stage W_ih slice (96 rows x 256)
    for (int f4 = tid; f4 < 96 * 64; f4 += 256) {
        int lr = f4 >> 6, c4 = f4 & 63;
        int grow = (lr >> 5) * HDIM + jt + (lr & 31);
        float4 v = ((const float4*)(W_ih + (size_t)grow * EDIM))[c4];
        ushort4 o; o.x = f2b(v.x); o.y = f2b(v.y); o.z = f2b(v.z); o.w = f2b(v.w);
        *(ushort4*)&Wih_l[lr * WIH_STRIDE + c4 * 4] = o;
    }
    __syncthreads();

    // A-operand pointers (A row = nl within this wave's 16-row tile)
    const int brow = g * BT + rt * 16 + nl;
    const unsigned short* xrow = x16 + (size_t)brow * S_LEN * EDIM + quad * 8;
    const size_t hoff = (size_t)brow * HDIM + quad * 8;

    // LDS B-fragment bases: row = gate*32 + ct*16 + nl
    int wih_b[3], whh_b[3];
    #pragma unroll
    for (int gg = 0; gg < 3; ++gg) {
        wih_b[gg] = (gg * 32 + ct * 16 + nl) * WIH_STRIDE + quad * 8;
        whh_b[gg] = (gg * 32 + ct * 16 + nl) * WHH_STRIDE + quad * 8;
    }

    // per-thread output column (C layout: col = nl) + biases
    const int jc = jt + ct * 16 + nl;
    const float bir = b_ih[jc],        bhr = b_hh[jc];
    const float biz = b_ih[512 + jc],  bhz = b_hh[512 + jc];
    const float bin = b_ih[1024 + jc], bhn = b_hh[1024 + jc];

    float hreg[4] = {0.f, 0.f, 0.f, 0.f};   // h carried in C layout (rows quad*4+r)
    // per-producer flag slots, 16B padded: this group's 16 flags
    int* myflag   = flags + ((g * 16 + ht) << 2);
    const int* pollflag = flags + ((g * 16 + (lane & 15)) << 2);  // wave0 poll addr
    int dead = 0;                           // wave0 spin dead-latch (safety net)

    // preload x A-fragments for step 0
    bf16x8 xf[8];
    #pragma unroll
    for (int kk = 0; kk < 8; ++kk) xf[kk] = *(const bf16x8*)(xrow + kk * 32);

    for (int s = 0; s < S_LEN; ++s) {
        f32x4 ar  = (f32x4){0.f,0.f,0.f,0.f};
        f32x4 az  = (f32x4){0.f,0.f,0.f,0.f};
        f32x4 anx = (f32x4){0.f,0.f,0.f,0.f};
        f32x4 anh = (f32x4){0.f,0.f,0.f,0.f};

        // ---- x-side GEMM for step s (overlaps producers of h[s] finishing)
        #pragma unroll
        for (int kk = 0; kk < 8; ++kk) {
            bf16x8 a = xf[kk];
            ar  = __builtin_amdgcn_mfma_f32_16x16x32_bf16(a, *(const bf16x8*)&Wih_l[wih_b[0] + kk * 32], ar,  0, 0, 0);
            az  = __builtin_amdgcn_mfma_f32_16x16x32_bf16(a, *(const bf16x8*)&Wih_l[wih_b[1] + kk * 32], az,  0, 0, 0);
            anx = __builtin_amdgcn_mfma_f32_16x16x32_bf16(a, *(const bf16x8*)&Wih_l[wih_b[2] + kk * 32], anx, 0, 0, 0);
        }

        // ---- wait for h[s]: all 16 producer flags >= s (same-XCD L2 poll)
        if (s > 0) {
            if (wave == 0 && !dead) {
                int it = 0;
                for (;;) {
                    int f = gld_b32_dev(pollflag);     // lanes 16-63 duplicate lanes 0-15
                    if (__all(f >= s)) break;
                    __builtin_amdgcn_s_sleep(1);
                    if (++it > SPIN_CAP) { dead = 1; break; }
                }
            }
            __syncthreads();
        }

        // ---- A-fragment loads of h[s] from this XCD's L2 (sc1: bypass L1)
        const unsigned short* hp = h16 + (size_t)(s & 1) * HBUF + hoff;
        u32x4 ha[16];
        #pragma unroll
        for (int kk = 0; kk < 16; ++kk) ha[kk] = gld_b128_dev(hp + kk * 32);
        wait_vm0();
        // rule #18: inline-asm loads are invisible to compiler waitcnt insertion;
        // "memory" clobber does not order register-only MFMAs. Pin MFMAs below.
        __builtin_amdgcn_sched_barrier(0);

        // ---- prefetch next step's x A-fragments (overlaps h-GEMM)
        if (s + 1 < S_LEN) {
            const unsigned short* xp = xrow + (size_t)(s + 1) * EDIM;
            #pragma unroll
            for (int kk = 0; kk < 8; ++kk) xf[kk] = *(const bf16x8*)(xp + kk * 32);
        }

        // ---- h-side GEMM
        #pragma unroll
        for (int kk = 0; kk < 16; ++kk) {
            union { u32x4 u; bf16x8 b; } cv; cv.u = ha[kk];
            bf16x8 a = cv.b;
            ar  = __builtin_amdgcn_mfma_f32_16x16x32_bf16(a, *(const bf16x8*)&Whh_l[whh_b[0] + kk * 32], ar,  0, 0, 0);
            az  = __builtin_amdgcn_mfma_f32_16x16x32_bf16(a, *(const bf16x8*)&Whh_l[whh_b[1] + kk * 32], az,  0, 0, 0);
            anh = __builtin_amdgcn_mfma_f32_16x16x32_bf16(a, *(const bf16x8*)&Whh_l[whh_b[2] + kk * 32], anh, 0, 0, 0);
        }

        // ---- gate math in C-layout registers (row = rt*16 + quad*4 + r, col = jc)
        #pragma unroll
        for (int r = 0; r < 4; ++r) {
            float rr = sigmoid_(ar[r] + bir + bhr);
            float zz = sigmoid_(az[r] + biz + bhz);
            float nn = tanh_(anx[r] + bin + rr * (anh[r] + bhn));
            float hn = (1.0f - zz) * nn + zz * hreg[r];
            hreg[r] = hn;
            hstage[(rt * 16 + quad * 4 + r) * HST_STRIDE + ct * 16 + nl] = f2b(hn);
        }
        __syncthreads();

        // ---- pack to 16B chunks, device-scope store into this XCD's L2
        if (tid < 128) {
            int row = tid >> 2, ch = tid & 3;
            u32x4 v = *(const u32x4*)&hstage[row * HST_STRIDE + ch * 8];
            unsigned short* dst = h16 + (size_t)((s + 1) & 1) * HBUF
                                + (size_t)(g * BT + row) * HDIM + jt + ch * 8;
            gst_b128_dev(v, dst);
        }
        wait_vm0();        // this thread's stores acked at L2
        __syncthreads();   // all threads' stores drained
        if (tid == 0) gst_b32_dev(s + 1, myflag);   // monotone release flag (L2)
    }

    // ---- final hidden state to fp32 global for the head
    #pragma unroll
    for (int r = 0; r < 4; ++r)
        h32_out[(size_t)(g * BT + rt * 16 + quad * 4 + r) * HDIM + jc] = hreg[r];
}

// ---------------------------------------------------------------- head: logits + softmax
__global__ __launch_bounds__(256) void out_head(const float* __restrict__ h32,
                                                const float* __restrict__ W_out,
                                                const float* __restrict__ b_out,
                                                float* __restrict__ out) {
    int b = blockIdx.x * blockDim.x + threadIdx.x;   // 0..511
    if (b >= BDIM) return;
    float acc[LOUT];
    #pragma unroll
    for (int l = 0; l < LOUT; ++l) acc[l] = b_out[l];
    const float4* hrow = (const float4*)(h32 + (size_t)b * HDIM);
    for (int k4 = 0; k4 < HDIM / 4; ++k4) {
        float4 hv = hrow[k4];
        #pragma unroll
        for (int l = 0; l < LOUT; ++l) {
            const float4 wv = ((const float4*)(W_out + l * HDIM))[k4];
            acc[l] += hv.x * wv.x + hv.y * wv.y + hv.z * wv.z + hv.w * wv.w;
        }
    }
    float m = acc[0];
    #pragma unroll
    for (int l = 1; l < LOUT; ++l) m = fmaxf(m, acc[l]);
    float sum = 0.f;
    #pragma unroll
    for (int l = 0; l < LOUT; ++l) { acc[l] = __expf(acc[l] - m); sum += acc[l]; }
    float inv = 1.0f / sum;
    float4 o0 = {acc[0] * inv, acc[1] * inv, acc[2] * inv, acc[3] * inv};
    float4 o1 = {acc[4] * inv, acc[5] * inv, acc[6] * inv, acc[7] * inv};
    ((float4*)(out + (size_t)b * LOUT))[0] = o0;
    ((float4*)(out + (size_t)b * LOUT))[1] = o1;
}

// ---------------------------------------------------------------- launch
extern "C" void kernel_launch(void* const* d_in, const int* in_sizes, int n_in,
                              void* d_out, int out_size, void* d_ws, size_t ws_size,
                              hipStream_t stream) {
    const float* x     = (const float*)d_in[0];
    const float* W_ih  = (const float*)d_in[1];
    const float* W_hh  = (const float*)d_in[2];
    const float* b_ih  = (const float*)d_in[3];
    const float* b_hh  = (const float*)d_in[4];
    const float* W_out = (const float*)d_in[5];
    const float* b_out = (const float*)d_in[6];
    float* out = (float*)d_out;

    char* w = (char*)d_ws;
    unsigned short* x16 = (unsigned short*)w;  w += (size_t)BDIM * S_LEN * EDIM * 2;  // 67 MB
    unsigned short* h16 = (unsigned short*)w;  w += (size_t)2 * HBUF * 2;             // 1 MB
    float* h32          = (float*)w;           w += (size_t)BDIM * HDIM * 4;          // 1 MB
    int* flags          = (int*)w;             w += (size_t)(NGRP * 16 * 4 + 16) * 4; // ~4 KB

    (void)hipMemsetAsync(flags, 0, (NGRP * 16 * 4 + 16) * sizeof(int), stream);
    (void)hipMemsetAsync(h16, 0, HBUF * sizeof(unsigned short), stream);  // h[0] = 0

    const int n4 = (BDIM * S_LEN * EDIM) / 4;
    cast_f32_bf16<<<8192, 256, 0, stream>>>(x, x16, n4);

    // 256 WGs x ~153 KB LDS: capacity-pins exactly 1 WG/CU => 32 WGs per XCD.
    gru_scan<<<256, 256, 0, stream>>>(W_ih, W_hh, b_ih, b_hh, x16, h16, h32, flags);

    out_head<<<2, 256, 0, stream>>>(h32, W_out, b_out, out);
}

// Round 7
// 1414.306 us; speedup vs baseline: 1.3372x; 1.0235x over previous
//
#include <hip/hip_runtime.h>
#include <hip/hip_bf16.h>

// Problem dims
#define S_LEN 256
#define EDIM  256
#define HDIM  512
#define BDIM  512
#define LOUT  8
// v7 = v6 + register-resident W_hh fragments.  (Resubmit: R6 bench was an
// infra failure -- "container failed twice" -- no kernel signal.)
// v6 post-mortem: coherence path (MALL vs XCD-L2) was NOT the bottleneck
// (v5 1273us vs v6 1250us). The serial critical path is LDS bandwidth:
// 288 ds_read_b128/step/CU for B-operands (~3456cy + 1178cy conflicts
// ~= 1.9us/step), of which the 192 h-side reads sit AFTER the rendezvous.
// Occupancy is LDS-pinned at 1 WG/CU = 1 wave/SIMD -> 512 VGPR/wave budget;
// current use 132. The h-side W frags are step-invariant: 48 frags x 4 VGPR
// = 192 regs. Load them ONCE after staging; h-GEMM becomes a pure-register
// MFMA burst (zero LDS on the critical path).
// x-side B stays in LDS (overlaps the rendezvous wait; keeps regs <450).
// Everything else identical to v6 (passing): XCD-claimed groups, sc1
// exchange on the XCD L2, per-producer monotone flags.
#define BT    32     // batch rows per group
#define HT    32     // h cols per WG
#define NHT   16     // WGs per group (barrier width)
#define NGRP  16
// LDS strides (bf16 elems). 520*2B=1040B row stride -> 2-way bank alias (free).
#define WHH_STRIDE 520
#define WIH_STRIDE 264
#define HST_STRIDE 40    // h staging, ushort elems (80B rows)
#define HBUF (BDIM * HDIM)   // elems per h bf16 buffer
#define SPIN_CAP 2000000     // safety net: dead-latch (fail, not hang)

typedef short bf16x8 __attribute__((ext_vector_type(8)));
typedef float f32x4  __attribute__((ext_vector_type(4)));
typedef unsigned int u32x4 __attribute__((ext_vector_type(4)));

__device__ __forceinline__ unsigned short f2b(float f) {
    unsigned u = __float_as_uint(f);
    u += 0x7FFFu + ((u >> 16) & 1u);   // round-to-nearest-even
    return (unsigned short)(u >> 16);
}
__device__ __forceinline__ float sigmoid_(float x) { return 1.0f / (1.0f + __expf(-x)); }
__device__ __forceinline__ float tanh_(float x)    { return 2.0f / (1.0f + __expf(-2.0f * x)) - 1.0f; }

// Device-scope (sc1) ops: bypass L1, served by the local XCD L2.
// Correct here because producer and consumer share that L2 (same XCD).
__device__ __forceinline__ void gst_b128_dev(u32x4 v, void* addr) {
    asm volatile("global_store_dwordx4 %0, %1, off sc1" :: "v"(addr), "v"(v) : "memory");
}
__device__ __forceinline__ u32x4 gld_b128_dev(const void* addr) {
    u32x4 v;
    asm volatile("global_load_dwordx4 %0, %1, off sc1" : "=&v"(v) : "v"(addr) : "memory");
    return v;
}
__device__ __forceinline__ void gst_b32_dev(int v, void* addr) {
    asm volatile("global_store_dword %0, %1, off sc1" :: "v"(addr), "v"(v) : "memory");
}
__device__ __forceinline__ int gld_b32_dev(const void* addr) {
    int v;
    asm volatile("global_load_dword %0, %1, off sc1\n\ts_waitcnt vmcnt(0)"
                 : "=&v"(v) : "v"(addr) : "memory");
    return v;
}
__device__ __forceinline__ void wait_vm0() {
    asm volatile("s_waitcnt vmcnt(0)" ::: "memory");
}

// ---------------------------------------------------------------- cast x -> bf16
__global__ __launch_bounds__(256) void cast_f32_bf16(const float* __restrict__ in,
                                                     unsigned short* __restrict__ out,
                                                     int n4) {
    int i = blockIdx.x * blockDim.x + threadIdx.x;
    int stride = gridDim.x * blockDim.x;
    for (int idx = i; idx < n4; idx += stride) {
        float4 v = ((const float4*)in)[idx];
        ushort4 o;
        o.x = f2b(v.x); o.y = f2b(v.y); o.z = f2b(v.z); o.w = f2b(v.w);
        ((ushort4*)out)[idx] = o;
    }
}

// ---------------------------------------------------------------- persistent GRU scan
__global__ __launch_bounds__(256, 1) void gru_scan(
    const float* __restrict__ W_ih, const float* __restrict__ W_hh,
    const float* __restrict__ b_ih, const float* __restrict__ b_hh,
    const unsigned short* __restrict__ x16,   // [B, S, E] bf16
    unsigned short* __restrict__ h16,         // 2 x [B, H] bf16 (double buffer)
    float* __restrict__ h32_out,              // [B, H] final hidden
    int* __restrict__ flags)                  // [NGRP*16*4] step flags + [16] claim cnts
{
    const int tid  = threadIdx.x;
    const int wave = tid >> 6;
    const int lane = tid & 63;
    const int quad = lane >> 4;
    const int nl   = lane & 15;
    const int rt   = wave & 1;   // row-tile (16 rows) within BT=32
    const int ct   = wave >> 1;  // col-tile (16 cols) within HT=32

    __shared__ unsigned short Whh_l[96 * WHH_STRIDE];  // [gate(3) x 32 cols] x 512 k  (99.8 KB)
    __shared__ unsigned short Wih_l[96 * WIH_STRIDE];  // [gate(3) x 32 cols] x 256 k  (50.7 KB)
    __shared__ unsigned short hstage[BT * HST_STRIDE]; // pack C-layout -> row-major 16B chunks
    __shared__ int role_s;

    // ---- claim a role on this physical XCD (1 WG/CU by LDS capacity => 32 WGs/XCD)
    int* cnt = flags + NGRP * 16 * 4;
    if (tid == 0) {
        unsigned xcc;
        asm volatile("s_getreg_b32 %0, hwreg(HW_REG_XCC_ID, 0, 32)" : "=s"(xcc));
        int xcd = (int)(xcc & 7u);
        int r = __hip_atomic_fetch_add(&cnt[xcd], 1, __ATOMIC_RELAXED,
                                       __HIP_MEMORY_SCOPE_AGENT);
        role_s = xcd * 32 + (r & 31);
    }
    __syncthreads();
    const int role = role_s;
    const int g  = (role >> 5) * 2 + ((role >> 4) & 1);  // group 0..15 (2 per XCD)
    const int ht = role & 15;                            // h-col slot within group
    const int jt = ht * HT;

    // ---- stage W_hh slice (96 rows x 512), fp32 -> bf16
    for (int f4 = tid; f4 < 96 * 128; f4 += 256) {
        int lr = f4 >> 7, c4 = f4 & 127;
        int grow = (lr >> 5) * HDIM + jt + (lr & 31);    // gate*512 + jt + c
        float4 v = ((const float4*)(W_hh + (size_t)grow * HDIM))[c4];
        ushort4 o; o.x = f2b(v.x); o.y = f2b(v.y); o.z = f2b(v.z); o.w = f2b(v.w);
        *(ushort4*)&Whh_l[lr * WHH_STRIDE + c4 * 4] = o;
    }
    // ---- stage W_ih slice (96 rows x 256)
    for (int f4 = tid; f4 < 96 * 64; f4 += 256) {
        int lr = f4 >> 6, c4 = f4 & 63;
        int grow = (lr >> 5) * HDIM + jt + (lr & 31);
        float4 v = ((const float4*)(W_ih + (size_t)grow * EDIM))[c4];
        ushort4 o; o.x = f2b(v.x); o.y = f2b(v.y); o.z = f2b(v.z); o.w = f2b(v.w);
        *(ushort4*)&Wih_l[lr * WIH_STRIDE + c4 * 4] = o;
    }
    __syncthreads();

    // A-operand pointers (A row = nl within this wave's 16-row tile)
    const int brow = g * BT + rt * 16 + nl;
    const unsigned short* xrow = x16 + (size_t)brow * S_LEN * EDIM + quad * 8;
    const size_t hoff = (size_t)brow * HDIM + quad * 8;

    // LDS B-fragment bases: row = gate*32 + ct*16 + nl
    int wih_b[3], whh_b[3];
    #pragma unroll
    for (int gg = 0; gg < 3; ++gg) {
        wih_b[gg] = (gg * 32 + ct * 16 + nl) * WIH_STRIDE + quad * 8;
        whh_b[gg] = (gg * 32 + ct * 16 + nl) * WHH_STRIDE + quad * 8;
    }

    // ---- hoist h-side W fragments into registers ONCE (step-invariant).
    // 48 frags x 4 VGPR = 192 regs; 1 wave/SIMD (LDS-pinned) gives ~512 budget.
    // Indices all compile-time constant after unroll (rule #20).
    bf16x8 wh[3][16];
    #pragma unroll
    for (int gg = 0; gg < 3; ++gg)
        #pragma unroll
        for (int kk = 0; kk < 16; ++kk)
            wh[gg][kk] = *(const bf16x8*)&Whh_l[whh_b[gg] + kk * 32];

    // per-thread output column (C layout: col = nl) + biases
    const int jc = jt + ct * 16 + nl;
    const float bir = b_ih[jc],        bhr = b_hh[jc];
    const float biz = b_ih[512 + jc],  bhz = b_hh[512 + jc];
    const float bin = b_ih[1024 + jc], bhn = b_hh[1024 + jc];

    float hreg[4] = {0.f, 0.f, 0.f, 0.f};   // h carried in C layout (rows quad*4+r)
    // per-producer flag slots, 16B padded: this group's 16 flags
    int* myflag   = flags + ((g * 16 + ht) << 2);
    const int* pollflag = flags + ((g * 16 + (lane & 15)) << 2);  // wave0 poll addr
    int dead = 0;                           // wave0 spin dead-latch (safety net)

    // preload x A-fragments for step 0
    bf16x8 xf[8];
    #pragma unroll
    for (int kk = 0; kk < 8; ++kk) xf[kk] = *(const bf16x8*)(xrow + kk * 32);

    for (int s = 0; s < S_LEN; ++s) {
        f32x4 ar  = (f32x4){0.f,0.f,0.f,0.f};
        f32x4 az  = (f32x4){0.f,0.f,0.f,0.f};
        f32x4 anx = (f32x4){0.f,0.f,0.f,0.f};
        f32x4 anh = (f32x4){0.f,0.f,0.f,0.f};

        // ---- x-side GEMM for step s (LDS B-reads; overlaps producers finishing)
        #pragma unroll
        for (int kk = 0; kk < 8; ++kk) {
            bf16x8 a = xf[kk];
            ar  = __builtin_amdgcn_mfma_f32_16x16x32_bf16(a, *(const bf16x8*)&Wih_l[wih_b[0] + kk * 32], ar,  0, 0, 0);
            az  = __builtin_amdgcn_mfma_f32_16x16x32_bf16(a, *(const bf16x8*)&Wih_l[wih_b[1] + kk * 32], az,  0, 0, 0);
            anx = __builtin_amdgcn_mfma_f32_16x16x32_bf16(a, *(const bf16x8*)&Wih_l[wih_b[2] + kk * 32], anx, 0, 0, 0);
        }

        // ---- wait for h[s]: all 16 producer flags >= s (same-XCD L2 poll)
        if (s > 0) {
            if (wave == 0 && !dead) {
                int it = 0;
                for (;;) {
                    int f = gld_b32_dev(pollflag);     // lanes 16-63 duplicate lanes 0-15
                    if (__all(f >= s)) break;
                    __builtin_amdgcn_s_sleep(1);
                    if (++it > SPIN_CAP) { dead = 1; break; }
                }
            }
            __syncthreads();
        }

        // ---- A-fragment loads of h[s] from this XCD's L2 (sc1: bypass L1)
        const unsigned short* hp = h16 + (size_t)(s & 1) * HBUF + hoff;
        u32x4 ha[16];
        #pragma unroll
        for (int kk = 0; kk < 16; ++kk) ha[kk] = gld_b128_dev(hp + kk * 32);
        wait_vm0();
        // rule #18: inline-asm loads are invisible to compiler waitcnt insertion;
        // "memory" clobber does not order register-only MFMAs. Pin MFMAs below.
        __builtin_amdgcn_sched_barrier(0);

        // ---- prefetch next step's x A-fragments (overlaps h-GEMM)
        if (s + 1 < S_LEN) {
            const unsigned short* xp = xrow + (size_t)(s + 1) * EDIM;
            #pragma unroll
            for (int kk = 0; kk < 8; ++kk) xf[kk] = *(const bf16x8*)(xp + kk * 32);
        }

        // ---- h-side GEMM: pure-register MFMA burst (B from wh regs, no LDS)
        #pragma unroll
        for (int kk = 0; kk < 16; ++kk) {
            union { u32x4 u; bf16x8 b; } cv; cv.u = ha[kk];
            bf16x8 a = cv.b;
            ar  = __builtin_amdgcn_mfma_f32_16x16x32_bf16(a, wh[0][kk], ar,  0, 0, 0);
            az  = __builtin_amdgcn_mfma_f32_16x16x32_bf16(a, wh[1][kk], az,  0, 0, 0);
            anh = __builtin_amdgcn_mfma_f32_16x16x32_bf16(a, wh[2][kk], anh, 0, 0, 0);
        }

        // ---- gate math in C-layout registers (row = rt*16 + quad*4 + r, col = jc)
        #pragma unroll
        for (int r = 0; r < 4; ++r) {
            float rr = sigmoid_(ar[r] + bir + bhr);
            float zz = sigmoid_(az[r] + biz + bhz);
            float nn = tanh_(anx[r] + bin + rr * (anh[r] + bhn));
            float hn = (1.0f - zz) * nn + zz * hreg[r];
            hreg[r] = hn;
            hstage[(rt * 16 + quad * 4 + r) * HST_STRIDE + ct * 16 + nl] = f2b(hn);
        }
        __syncthreads();

        // ---- pack to 16B chunks, device-scope store into this XCD's L2
        if (tid < 128) {
            int row = tid >> 2, ch = tid & 3;
            u32x4 v = *(const u32x4*)&hstage[row * HST_STRIDE + ch * 8];
            unsigned short* dst = h16 + (size_t)((s + 1) & 1) * HBUF
                                + (size_t)(g * BT + row) * HDIM + jt + ch * 8;
            gst_b128_dev(v, dst);
        }
        wait_vm0();        // this thread's stores acked at L2
        __syncthreads();   // all threads' stores drained
        if (tid == 0) gst_b32_dev(s + 1, myflag);   // monotone release flag (L2)
    }

    // ---- final hidden state to fp32 global for the head
    #pragma unroll
    for (int r = 0; r < 4; ++r)
        h32_out[(size_t)(g * BT + rt * 16 + quad * 4 + r) * HDIM + jc] = hreg[r];
}

// ---------------------------------------------------------------- head: logits + softmax
__global__ __launch_bounds__(256) void out_head(const float* __restrict__ h32,
                                                const float* __restrict__ W_out,
                                                const float* __restrict__ b_out,
                                                float* __restrict__ out) {
    int b = blockIdx.x * blockDim.x + threadIdx.x;   // 0..511
    if (b >= BDIM) return;
    float acc[LOUT];
    #pragma unroll
    for (int l = 0; l < LOUT; ++l) acc[l] = b_out[l];
    const float4* hrow = (const float4*)(h32 + (size_t)b * HDIM);
    for (int k4 = 0; k4 < HDIM / 4; ++k4) {
        float4 hv = hrow[k4];
        #pragma unroll
        for (int l = 0; l < LOUT; ++l) {
            const float4 wv = ((const float4*)(W_out + l * HDIM))[k4];
            acc[l] += hv.x * wv.x + hv.y * wv.y + hv.z * wv.z + hv.w * wv.w;
        }
    }
    float m = acc[0];
    #pragma unroll
    for (int l = 1; l < LOUT; ++l) m = fmaxf(m, acc[l]);
    float sum = 0.f;
    #pragma unroll
    for (int l = 0; l < LOUT; ++l) { acc[l] = __expf(acc[l] - m); sum += acc[l]; }
    float inv = 1.0f / sum;
    float4 o0 = {acc[0] * inv, acc[1] * inv, acc[2] * inv, acc[3] * inv};
    float4 o1 = {acc[4] * inv, acc[5] * inv, acc[6] * inv, acc[7] * inv};
    ((float4*)(out + (size_t)b * LOUT))[0] = o0;
    ((float4*)(out + (size_t)b * LOUT))[1] = o1;
}

// ---------------------------------------------------------------- launch
extern "C" void kernel_launch(void* const* d_in, const int* in_sizes, int n_in,
                              void* d_out, int out_size, void* d_ws, size_t ws_size,
                              hipStream_t stream) {
    const float* x     = (const float*)d_in[0];
    const float* W_ih  = (const float*)d_in[1];
    const float* W_hh  = (const float*)d_in[2];
    const float* b_ih  = (const float*)d_in[3];
    const float* b_hh  = (const float*)d_in[4];
    const float* W_out = (const float*)d_in[5];
    const float* b_out = (const float*)d_in[6];
    float* out = (float*)d_out;

    char* w = (char*)d_ws;
    unsigned short* x16 = (unsigned short*)w;  w += (size_t)BDIM * S_LEN * EDIM * 2;  // 67 MB
    unsigned short* h16 = (unsigned short*)w;  w += (size_t)2 * HBUF * 2;             // 1 MB
    float* h32          = (float*)w;           w += (size_t)BDIM * HDIM * 4;          // 1 MB
    int* flags          = (int*)w;             w += (size_t)(NGRP * 16 * 4 + 16) * 4; // ~4 KB

    (void)hipMemsetAsync(flags, 0, (NGRP * 16 * 4 + 16) * sizeof(int), stream);
    (void)hipMemsetAsync(h16, 0, HBUF * sizeof(unsigned short), stream);  // h[0] = 0

    const int n4 = (BDIM * S_LEN * EDIM) / 4;
    cast_f32_bf16<<<8192, 256, 0, stream>>>(x, x16, n4);

    // 256 WGs x ~153 KB LDS: capacity-pins exactly 1 WG/CU => 32 WGs per XCD.
    gru_scan<<<256, 256, 0, stream>>>(W_ih, W_hh, b_ih, b_hh, x16, h16, h32, flags);

    out_head<<<2, 256, 0, stream>>>(h32, W_out, b_out, out);
}